// Round 3
// baseline (508.702 us; speedup 1.0000x reference)
//
#include <hip/hip_runtime.h>

typedef unsigned int  u32;
typedef unsigned short u16;
typedef __bf16 bf16x8 __attribute__((ext_vector_type(8)));
typedef float  f32x4  __attribute__((ext_vector_type(4)));

// ---- output float offsets (return-order concat) ----
#define O1 16777216    // updated_memory [1024,512]
#define O2 17301504    // sq [16384,1024]  (used as S scratch first, overwritten in place)
#define O3 34078720    // sm [16384,1024]
#define O4 50855936    // diversity_loss_updated
#define O5 50855937    // similarity_loss

// ---- ws byte offsets ----
#define WS_QHI   0u
#define WS_QLO   16777216u
#define WS_KHI   33554432u
#define WS_KLO   34603008u
#define WS_KT    35651584u
#define WS_KNORM 36700160u
#define WS_CNT   36704256u   // u32[1024]
#define WS_OFFS  36708352u   // u32[1025]
#define WS_CUR   36712704u   // u32[1024]
#define WS_RN    36769792u
#define WS_PMAX  36835328u   // reused as list[16384]
#define WS_CMAX  36966400u
#define WS_CSUM  36970496u
#define WS_ARGM  36974592u
#define WS_WGT   37040128u
#define WS_EMAX  37199872u   // f32[32] maxent partials
#define WS_SCAL  39202816u   // [0]=sim_acc [1]=maxent [2]=div_acc [3]=diag_acc
#define WS_PM2   39203840u   // pmax2 [128][1024] f32 = 512KB
#define WS_PS2   39728128u   // psum2 [128][1024] f32 = 512KB
#define WS_SM16  40252416u   // sm bf16 [16384][1024] = 32MB  (ends ~73.8MB)

__device__ __forceinline__ u16 bf_rne(float f){
  u32 u = __float_as_uint(f);
  u32 r = u + 0x7fffu + ((u >> 16) & 1u);
  return (u16)(r >> 16);
}
__device__ __forceinline__ float bf_f(u16 h){ return __uint_as_float(((u32)h) << 16); }

__device__ __forceinline__ void glds16(const void* g, void* l){
  __builtin_amdgcn_global_load_lds((const __attribute__((address_space(1))) u32*)g,
                                   (__attribute__((address_space(3))) u32*)l, 16, 0, 0);
}

// ---------------- merged preamble: keys norm/split | keysT | maxent partials | phaseA ----------------
__global__ __launch_bounds__(256) void k_pre(
    const float* __restrict__ keys, const float* __restrict__ ent,
    const float* __restrict__ query, float* __restrict__ out0,
    u16* __restrict__ khi, u16* __restrict__ klo, float* __restrict__ knorm,
    u16* __restrict__ kT, float* __restrict__ emax,
    u16* __restrict__ qhi, u16* __restrict__ qlo, float* __restrict__ rn_g){
  __shared__ float shmem[64*65 + 256 + 64];
  float* tile = shmem;
  float* red  = shmem + 64*65;
  float* sinv = red + 256;
  int bx = blockIdx.x; int t = threadIdx.x;

  if (bx < 256){
    int wave = t >> 6, l = t & 63;
    int m = bx*4 + wave;
    const float* kr = keys + (size_t)m*512 + l*8;
    float f[8];
    #pragma unroll
    for (int i=0;i<8;i++) f[i] = kr[i];
    float ss = 0.f;
    #pragma unroll
    for (int i=0;i<8;i++) ss += f[i]*f[i];
    for (int o=32;o>0;o>>=1) ss += __shfl_xor(ss,o);
    if (l == 0) knorm[m] = sqrtf(ss);
    u32 hh[4], ll[4];
    #pragma unroll
    for (int i=0;i<4;i++){
      u16 h0 = bf_rne(f[2*i]);   u16 l0 = bf_rne(f[2*i]   - bf_f(h0));
      u16 h1 = bf_rne(f[2*i+1]); u16 l1 = bf_rne(f[2*i+1] - bf_f(h1));
      hh[i] = (u32)h0 | ((u32)h1<<16);
      ll[i] = (u32)l0 | ((u32)l1<<16);
    }
    *(uint4*)&khi[(size_t)m*512 + l*8] = make_uint4(hh[0],hh[1],hh[2],hh[3]);
    *(uint4*)&klo[(size_t)m*512 + l*8] = make_uint4(ll[0],ll[1],ll[2],ll[3]);
  } else if (bx < 384){
    int g = bx - 256;
    int m0 = (g & 15)*64, c0 = (g >> 4)*64;
    int j = t & 63; int ig = t >> 6;
    #pragma unroll 4
    for (int ii=0; ii<16; ++ii){
      int i = ig*16 + ii;
      tile[i*65 + j] = keys[(size_t)(m0+i)*512 + c0 + j];
    }
    __syncthreads();
    #pragma unroll 4
    for (int ii=0; ii<16; ++ii){
      int i = ig*16 + ii;
      kT[(size_t)(c0+i)*1024 + m0 + j] = bf_rne(tile[j*65 + i]);
    }
  } else if (bx < 416){
    int g = bx - 384;
    int i = g*512 + t;
    float v = fmaxf(ent[i], ent[i + 256]);
    for (int o=32;o>0;o>>=1) v = fmaxf(v, __shfl_xor(v,o));
    if ((t & 63) == 0) red[t>>6] = v;
    __syncthreads();
    if (t == 0) emax[g] = fmaxf(fmaxf(red[0],red[1]), fmaxf(red[2],red[3]));
  } else {
    int bx2 = bx - 416;
    int b = bx2 >> 4; int hw0 = (bx2 & 15)*64;
    int hw = t & 63; int cg = t >> 6;
    const float* qb = query + (size_t)b*524288 + hw0 + hw;
    float p = 0.f;
    for (int c = cg; c < 512; c += 4){ float v = qb[(size_t)c*1024]; p += v*v; }
    red[cg*64 + hw] = p;
    __syncthreads();
    if (t < 64){
      float ss = red[t] + red[64+t] + red[128+t] + red[192+t];
      float nrm = sqrtf(ss);
      float inv = 1.0f / fmaxf(nrm, 1e-12f);
      sinv[t] = inv;
      rn_g[b*1024 + hw0 + t] = nrm * inv;
    }
    __syncthreads();
    int nl = t >> 2, cq = t & 3;
    int n = b*1024 + hw0 + nl;
    float invv = sinv[hw];
    for (int cb = 0; cb < 8; ++cb){
      int cbase = cb*64;
      #pragma unroll 4
      for (int i = 0; i < 16; ++i){
        int cl = cg*16 + i;
        int c = cbase + cl;
        float v = query[(size_t)b*524288 + (size_t)c*1024 + hw0 + hw] * invv;
        tile[cl*65 + hw] = v;
        out0[(size_t)b*1048576 + (size_t)c*1024 + hw0 + hw] = v;
      }
      __syncthreads();
      u32 hh[8], ll[8];
      #pragma unroll
      for (int p2 = 0; p2 < 8; ++p2){
        float f0 = tile[(cq*16 + p2*2)*65 + nl];
        float f1 = tile[(cq*16 + p2*2 + 1)*65 + nl];
        u16 h0 = bf_rne(f0); u16 lo0 = bf_rne(f0 - bf_f(h0));
        u16 h1 = bf_rne(f1); u16 lo1 = bf_rne(f1 - bf_f(h1));
        hh[p2] = (u32)h0 | ((u32)h1 << 16);
        ll[p2] = (u32)lo0 | ((u32)lo1 << 16);
      }
      size_t base = (size_t)n*512 + cbase + cq*16;
      *(uint4*)&qhi[base]     = make_uint4(hh[0],hh[1],hh[2],hh[3]);
      *(uint4*)&qhi[base + 8] = make_uint4(hh[4],hh[5],hh[6],hh[7]);
      *(uint4*)&qlo[base]     = make_uint4(ll[0],ll[1],ll[2],ll[3]);
      *(uint4*)&qlo[base + 8] = make_uint4(ll[4],ll[5],ll[6],ll[7]);
      __syncthreads();
    }
  }
}

// ---------------- score GEMM: S = qr @ keys^T, split-bf16 (3 MFMA terms) ----------------
// Double-buffered 2-phase schedule (BK=32): STAGE(next) issued before COMPUTE(cur),
// one barrier per K-step. XCD-swizzled. Fused column-softmax partial epilogue.
__global__ __launch_bounds__(256) void k_score(const u16* __restrict__ qhi, const u16* __restrict__ qlo,
    const u16* __restrict__ khi, const u16* __restrict__ klo, float* __restrict__ S,
    float* __restrict__ pm2, float* __restrict__ ps2){
  __shared__ u16 sAh[8192], sAl[8192], sBh[8192], sBl[8192];  // each [2 buf][4096] = 16KB
  int tid = threadIdx.x;
  int wg = ((blockIdx.x & 7) << 7) + (blockIdx.x >> 3);   // bijective XCD swizzle (1024 wgs)
  int nt = wg >> 3, mt = wg & 7;
  int nBase = nt*128, mBase = mt*128;
  int wave = tid >> 6, lane = tid & 63;
  int rw = (wave>>1)*64, cw = (wave&1)*64;
  int m16 = lane & 15, q4 = lane >> 4;
  f32x4 acc[4][4] = {};

  int row2 = tid >> 2;     // 0..63
  int cg4  = tid & 3;      // k-group slot within row
  auto STAGE = [&](int d, int kk){
    int k0 = kk*32;
    #pragma unroll
    for (int it=0; it<2; ++it){
      int row = it*64 + row2;
      int gs = cg4 ^ ((row >> 1) & 3);          // source-side swizzle (involution)
      size_t ka = (size_t)k0 + gs*8;
      int lo = d*4096 + it*2048 + tid*8;        // linear LDS dest (lane*16B)
      glds16(qhi + (size_t)(nBase + row)*512 + ka, &sAh[lo]);
      glds16(qlo + (size_t)(nBase + row)*512 + ka, &sAl[lo]);
      glds16(khi + (size_t)(mBase + row)*512 + ka, &sBh[lo]);
      glds16(klo + (size_t)(mBase + row)*512 + ka, &sBl[lo]);
    }
  };
  STAGE(0, 0);
  __syncthreads();
  for (int kit = 0; kit < 16; ++kit){
    int cur = kit & 1;
    if (kit < 15) STAGE(cur^1, kit+1);
    bf16x8 a0[4], a1[4], b0[4], b1[4];
    #pragma unroll
    for (int i=0;i<4;i++){
      int r = rw + i*16 + m16;
      int off = cur*4096 + r*32 + (q4 ^ ((r>>1)&3))*8;   // matches STAGE swizzle
      a0[i] = *(const bf16x8*)&sAh[off];
      a1[i] = *(const bf16x8*)&sAl[off];
    }
    #pragma unroll
    for (int j=0;j<4;j++){
      int r = cw + j*16 + m16;
      int off = cur*4096 + r*32 + (q4 ^ ((r>>1)&3))*8;
      b0[j] = *(const bf16x8*)&sBh[off];
      b1[j] = *(const bf16x8*)&sBl[off];
    }
    // 3 term-passes of 16 independent MFMAs each (no back-to-back same-acc chains)
    #pragma unroll
    for (int i=0;i<4;i++)
      #pragma unroll
      for (int j=0;j<4;j++)
        acc[i][j] = __builtin_amdgcn_mfma_f32_16x16x32_bf16(a0[i], b0[j], acc[i][j], 0,0,0);
    #pragma unroll
    for (int i=0;i<4;i++)
      #pragma unroll
      for (int j=0;j<4;j++)
        acc[i][j] = __builtin_amdgcn_mfma_f32_16x16x32_bf16(a0[i], b1[j], acc[i][j], 0,0,0);
    #pragma unroll
    for (int i=0;i<4;i++)
      #pragma unroll
      for (int j=0;j<4;j++)
        acc[i][j] = __builtin_amdgcn_mfma_f32_16x16x32_bf16(a1[i], b0[j], acc[i][j], 0,0,0);
    __syncthreads();
  }
  // ---- S store ----
  #pragma unroll
  for (int i=0;i<4;i++){
    int rbase = nBase + rw + i*16 + q4*4;
    #pragma unroll
    for (int j=0;j<4;j++){
      int col = mBase + cw + j*16 + m16;
      #pragma unroll
      for (int r=0;r<4;r++)
        S[(size_t)(rbase + r)*1024 + col] = acc[i][j][r];
    }
  }
  // ---- fused column-softmax partials over this block's 128 rows ----
  float* lm = (float*)sAh;        // [4 waves][4 j][16 m16]
  float* ls = lm + 256;
  #pragma unroll
  for (int j=0;j<4;j++){
    float cm = -3.4e38f;
    #pragma unroll
    for (int i=0;i<4;i++)
      #pragma unroll
      for (int r=0;r<4;r++) cm = fmaxf(cm, acc[i][j][r]);
    cm = fmaxf(cm, __shfl_xor(cm, 16));
    cm = fmaxf(cm, __shfl_xor(cm, 32));
    float cs = 0.f;
    #pragma unroll
    for (int i=0;i<4;i++)
      #pragma unroll
      for (int r=0;r<4;r++) cs += __expf(acc[i][j][r] - cm);
    cs += __shfl_xor(cs, 16);
    cs += __shfl_xor(cs, 32);
    if (lane < 16){
      lm[(wave*4 + j)*16 + m16] = cm;
      ls[(wave*4 + j)*16 + m16] = cs;
    }
  }
  __syncthreads();
  if (tid < 128){
    int w = tid >> 6;
    int x = tid & 63;
    int j = x >> 4, c16 = x & 15;
    float m0 = lm[(w*4 + j)*16 + c16],     s0 = ls[(w*4 + j)*16 + c16];
    float m1 = lm[((w+2)*4 + j)*16 + c16], s1 = ls[((w+2)*4 + j)*16 + c16];
    float M  = fmaxf(m0, m1);
    float Sv = s0*__expf(m0 - M) + s1*__expf(m1 - M);
    int col = mBase + w*64 + j*16 + c16;
    pm2[nt*1024 + col] = M;
    ps2[nt*1024 + col] = Sv;
  }
}

// ---------------- column finalize + housekeeping (count/scal zero, maxent reduce) ----------------
__global__ __launch_bounds__(256) void k_colfin(const float* __restrict__ pm2, const float* __restrict__ ps2,
    float* __restrict__ cmax, float* __restrict__ csum,
    const float* __restrict__ emax, float* __restrict__ scal, u32* __restrict__ count){
  int bx = blockIdx.x, t = threadIdx.x;
  if (bx < 4) count[bx*256 + t] = 0u;
  if (bx == 4 && t == 0){
    float mx = emax[0];
    for (int i=1;i<32;i++) mx = fmaxf(mx, emax[i]);
    scal[0] = 0.f; scal[1] = mx; scal[2] = 0.f; scal[3] = 0.f;
  }
  int col = bx*64 + (t & 63);
  int grp = t >> 6;
  float M = -3.4e38f, s = 0.f;
  for (int ch = grp*32; ch < grp*32 + 32; ++ch){
    float mi = pm2[ch*1024 + col], si = ps2[ch*1024 + col];
    float nm = fmaxf(M, mi);
    s = s*__expf(M - nm) + si*__expf(mi - nm);
    M = nm;
  }
  __shared__ float gm[256], gs[256];
  gm[t] = M; gs[t] = s;
  __syncthreads();
  if (t < 64){
    float MM = gm[t], ss2 = gs[t];
    #pragma unroll
    for (int g2=1; g2<4; ++g2){
      float mi = gm[g2*64 + t], si = gs[g2*64 + t];
      float nm = fmaxf(MM, mi);
      ss2 = ss2*__expf(MM - nm) + si*__expf(mi - nm);
      MM = nm;
    }
    cmax[col] = MM; csum[col] = ss2;
  }
}

// ---------------- row softmax: sm out (+bf16 copy), sq in-place over S, argmax/cos/w/count ----------------
__global__ __launch_bounds__(256) void k_row(float* __restrict__ S, float* __restrict__ sm,
    u16* __restrict__ sm16,
    const float* __restrict__ cmax, const float* __restrict__ csum,
    const float* __restrict__ rn, const float* __restrict__ knorm,
    const float* __restrict__ ent, const float* __restrict__ scal,
    int* __restrict__ argm, float* __restrict__ wgt, u32* __restrict__ count,
    float* __restrict__ sim_acc){
  int wave = threadIdx.x >> 6, lane = threadIdx.x & 63;
  int n = blockIdx.x*4 + wave;
  float4 v[4];
  const float4* Sr = (const float4*)(S + (size_t)n*1024);
  #pragma unroll
  for (int j=0;j<4;j++) v[j] = Sr[j*64 + lane];
  float m = -3.4e38f; int gi = 0;
  #pragma unroll
  for (int j=0;j<4;j++){
    int c0 = j*256 + lane*4;
    if (v[j].x > m){ m=v[j].x; gi=c0; }
    if (v[j].y > m){ m=v[j].y; gi=c0+1; }
    if (v[j].z > m){ m=v[j].z; gi=c0+2; }
    if (v[j].w > m){ m=v[j].w; gi=c0+3; }
  }
  for (int o=32;o>0;o>>=1){
    float om = __shfl_xor(m,o); int oi = __shfl_xor(gi,o);
    if (om > m || (om == m && oi < gi)){ m = om; gi = oi; }
  }
  float4 e[4]; float s = 0.f;
  #pragma unroll
  for (int j=0;j<4;j++){
    e[j].x = __expf(v[j].x - m); e[j].y = __expf(v[j].y - m);
    e[j].z = __expf(v[j].z - m); e[j].w = __expf(v[j].w - m);
    s += e[j].x + e[j].y + e[j].z + e[j].w;
  }
  for (int o=32;o>0;o>>=1) s += __shfl_xor(s,o);
  float ri = 1.f/s;
  float4* smr = (float4*)(sm + (size_t)n*1024);
  #pragma unroll
  for (int j=0;j<4;j++){
    float4 t2; t2.x=e[j].x*ri; t2.y=e[j].y*ri; t2.z=e[j].z*ri; t2.w=e[j].w*ri;
    smr[j*64 + lane] = t2;
    u32 w0 = (u32)bf_rne(t2.x) | ((u32)bf_rne(t2.y) << 16);
    u32 w1 = (u32)bf_rne(t2.z) | ((u32)bf_rne(t2.w) << 16);
    *(uint2*)&sm16[(size_t)n*1024 + j*256 + lane*4] = make_uint2(w0, w1);
  }
  float4* sqr = (float4*)(S + (size_t)n*1024);
  #pragma unroll
  for (int j=0;j<4;j++){
    int c0 = j*256 + lane*4;
    float4 cm = *(const float4*)(cmax + c0);
    float4 cs = *(const float4*)(csum + c0);
    float4 q;
    q.x = __expf(v[j].x - cm.x)/cs.x;
    q.y = __expf(v[j].y - cm.y)/cs.y;
    q.z = __expf(v[j].z - cm.z)/cs.z;
    q.w = __expf(v[j].w - cm.w)/cs.w;
    sqr[j*64 + lane] = q;
  }
  __shared__ float simw[4];
  if (lane == 0){
    float en = ent[n];
    float cosv = m / fmaxf(rn[n]*knorm[gi], 1e-8f);
    simw[wave] = (1.f - cosv)*en;
    float w = __expf(m - cmax[gi]) * en / scal[1];
    wgt[n] = w; argm[n] = gi;
    atomicAdd(&count[gi], 1u);
  }
  __syncthreads();
  if (threadIdx.x == 0)
    atomicAdd(sim_acc, simw[0]+simw[1]+simw[2]+simw[3]);
}

// ---------------- exclusive scan of 1024 counts -> offs + cursor ----------------
__global__ __launch_bounds__(256) void k_scan(const u32* __restrict__ count,
    u32* __restrict__ offs, u32* __restrict__ cursor){
  int t = threadIdx.x;
  u32 v0 = count[t*4], v1 = count[t*4+1], v2 = count[t*4+2], v3 = count[t*4+3];
  u32 s = v0+v1+v2+v3;
  u32 x = s;
  for (int o=1;o<64;o<<=1){ u32 y = __shfl_up(x,o); if ((t&63) >= o) x += y; }
  __shared__ u32 wsum[4];
  if ((t&63) == 63) wsum[t>>6] = x;
  __syncthreads();
  u32 wb = 0;
  for (int wv=0; wv < (t>>6); ++wv) wb += wsum[wv];
  u32 excl = wb + x - s;
  u32 o0 = excl, o1 = excl+v0, o2 = excl+v0+v1, o3 = excl+v0+v1+v2;
  offs[t*4]=o0; offs[t*4+1]=o1; offs[t*4+2]=o2; offs[t*4+3]=o3;
  cursor[t*4]=o0; cursor[t*4+1]=o1; cursor[t*4+2]=o2; cursor[t*4+3]=o3;
  if (t == 255) offs[1024] = 16384u;
}

// ---------------- bucket fill ----------------
__global__ __launch_bounds__(256) void k_bucket(const int* __restrict__ argm,
    u32* __restrict__ cursor, u32* __restrict__ list){
  int n = blockIdx.x*256 + threadIdx.x;
  int g = argm[n];
  u32 pos = atomicAdd(&cursor[g], 1u);
  list[pos] = n;
}

// ---------------- gather segment-sum + fused fnorm: out1 = l2norm(sum + keys) ----------------
__global__ __launch_bounds__(128) void k_gather(const u16* __restrict__ qhi, const u16* __restrict__ qlo,
    const u32* __restrict__ offs, const u32* __restrict__ list, const float* __restrict__ wgt,
    const float* __restrict__ keys, float* __restrict__ out1, float* __restrict__ scal){
  int m = blockIdx.x, t = threadIdx.x;
  int c0 = t*4;
  float a0=0.f,a1=0.f,a2=0.f,a3=0.f;
  u32 beg = offs[m], end = offs[m+1];
  for (u32 r = beg; r < end; ++r){
    int n = (int)list[r];
    float w = wgt[n];
    uint2 hh = *(const uint2*)&qhi[(size_t)n*512 + c0];
    uint2 ll = *(const uint2*)&qlo[(size_t)n*512 + c0];
    float f0 = bf_f((u16)(hh.x & 0xffffu)) + bf_f((u16)(ll.x & 0xffffu));
    float f1 = bf_f((u16)(hh.x >> 16))     + bf_f((u16)(ll.x >> 16));
    float f2 = bf_f((u16)(hh.y & 0xffffu)) + bf_f((u16)(ll.y & 0xffffu));
    float f3 = bf_f((u16)(hh.y >> 16))     + bf_f((u16)(ll.y >> 16));
    a0 += w*f0; a1 += w*f1; a2 += w*f2; a3 += w*f3;
  }
  float4 k4 = *(const float4*)(keys + (size_t)m*512 + c0);
  float u0 = a0 + k4.x, u1 = a1 + k4.y, u2 = a2 + k4.z, u3 = a3 + k4.w;
  float ss = u0*u0 + u1*u1 + u2*u2 + u3*u3;
  for (int o=32;o>0;o>>=1) ss += __shfl_xor(ss,o);
  __shared__ float r2[2];
  if ((t&63) == 0) r2[t>>6] = ss;
  __syncthreads();
  float tot = r2[0] + r2[1];
  float inv = 1.f / fmaxf(sqrtf(tot), 1e-12f);
  float4 o4; o4.x=u0*inv; o4.y=u1*inv; o4.z=u2*inv; o4.w=u3*inv;
  *(float4*)(out1 + (size_t)m*512 + c0) = o4;
  if (t == 0){
    float s2 = tot*inv*inv;
    atomicAdd(scal + 3, s2*s2);
  }
}

// ---------------- concat GEMM: out0 upper half = (sm @ keys) transposed to BCHW ----------------
// Double-buffered 2-phase schedule (BK=32), XCD-swizzled.
__global__ __launch_bounds__(256) void k_concat(const u16* __restrict__ kT, const u16* __restrict__ sm16,
    float* __restrict__ out0){
  __shared__ u16 sA[8192];       // [2 buf][4096] keysT tiles 128x32 (swizzled)
  __shared__ u16 sB[8192];       // [2 buf][4096] sm16 tiles 128x32 (swizzled)
  int tid = threadIdx.x;
  int wg = ((blockIdx.x & 7) << 6) + (blockIdx.x >> 3);   // bijective XCD swizzle (512 wgs)
  int ct = wg & 3, nt = wg >> 2;
  int cBase = ct*128, nBase = nt*128;
  int wave = tid>>6, lane = tid&63;
  int rw = (wave>>1)*64, cw = (wave&1)*64;
  int m16 = lane&15, q4 = lane>>4;
  f32x4 acc[4][4] = {};

  int row2 = tid >> 2;
  int cg4  = tid & 3;
  auto STAGE = [&](int d, int kk){
    int k0 = kk*32;
    #pragma unroll
    for (int it=0; it<2; ++it){
      int row = it*64 + row2;
      int gs = cg4 ^ ((row >> 1) & 3);
      size_t ka = (size_t)k0 + gs*8;
      int lo = d*4096 + it*2048 + tid*8;
      glds16(kT   + (size_t)(cBase + row)*1024 + ka, &sA[lo]);
      glds16(sm16 + (size_t)(nBase + row)*1024 + ka, &sB[lo]);
    }
  };
  STAGE(0, 0);
  __syncthreads();
  for (int kit=0; kit<32; ++kit){
    int cur = kit & 1;
    if (kit < 31) STAGE(cur^1, kit+1);
    bf16x8 a[4], b[4];
    #pragma unroll
    for (int i=0;i<4;i++){
      int r = rw + i*16 + m16;
      a[i] = *(const bf16x8*)&sA[cur*4096 + r*32 + (q4 ^ ((r>>1)&3))*8];
    }
    #pragma unroll
    for (int j=0;j<4;j++){
      int r = cw + j*16 + m16;
      b[j] = *(const bf16x8*)&sB[cur*4096 + r*32 + (q4 ^ ((r>>1)&3))*8];
    }
    #pragma unroll
    for (int i=0;i<4;i++)
      #pragma unroll
      for (int j=0;j<4;j++)
        acc[i][j] = __builtin_amdgcn_mfma_f32_16x16x32_bf16(a[i], b[j], acc[i][j], 0,0,0);
    __syncthreads();
  }
  #pragma unroll
  for (int i=0;i<4;i++){
    int c = cBase + rw + i*16 + q4*4;
    #pragma unroll
    for (int j=0;j<4;j++){
      int n = nBase + cw + j*16 + m16;
      int b2 = n >> 10, hw = n & 1023;
      #pragma unroll
      for (int r=0;r<4;r++)
        out0[(size_t)b2*1048576 + (size_t)(512 + c + r)*1024 + hw] = acc[i][j][r];
    }
  }
}

// ---------------- gram diversity: sum over (c1,c2) of (U^T U)^2 ----------------
__global__ __launch_bounds__(256) void k_gram(const float* __restrict__ U, float* __restrict__ scal){
  __shared__ float Ua[64*34], Ub[64*34];
  int bx = blockIdx.x & 15, by = blockIdx.x >> 4;
  int t = threadIdx.x;
  int c1 = (t >> 4)*2, c2 = (t & 15)*2;
  float d00=0,d01=0,d10=0,d11=0;
  for (int ch=0; ch<16; ++ch){
    #pragma unroll
    for (int j=0;j<8;j++){
      int flat = j*256 + t;
      int ml = flat >> 5, c = flat & 31;
      Ua[ml*34 + c] = U[(size_t)(ch*64 + ml)*512 + bx*32 + c];
      Ub[ml*34 + c] = U[(size_t)(ch*64 + ml)*512 + by*32 + c];
    }
    __syncthreads();
    #pragma unroll 8
    for (int ml=0; ml<64; ++ml){
      float2 a = *(const float2*)&Ua[ml*34 + c1];
      float2 b = *(const float2*)&Ub[ml*34 + c2];
      d00 += a.x*b.x; d01 += a.x*b.y; d10 += a.y*b.x; d11 += a.y*b.y;
    }
    __syncthreads();
  }
  float loc = d00*d00 + d01*d01 + d10*d10 + d11*d11;
  for (int o=32;o>0;o>>=1) loc += __shfl_xor(loc,o);
  __shared__ float r4[4];
  if ((t&63) == 0) r4[t>>6] = loc;
  __syncthreads();
  if (t == 0) atomicAdd(scal + 2, r4[0]+r4[1]+r4[2]+r4[3]);
}

// ---------------- final scalars ----------------
__global__ void k_final(const float* __restrict__ scal, float* __restrict__ out){
  out[O4] = (scal[2] - scal[3]) * (1.0f/1047552.0f);
  out[O5] = scal[0];
}

extern "C" void kernel_launch(void* const* d_in, const int* in_sizes, int n_in,
                              void* d_out, int out_size, void* d_ws, size_t ws_size,
                              hipStream_t stream) {
  const float* query = (const float*)d_in[0];
  const float* keys  = (const float*)d_in[1];
  const float* ent   = (const float*)d_in[2];
  float* out  = (float*)d_out;
  char*  ws   = (char*)d_ws;

  u16*   qhi   = (u16*)(ws + WS_QHI);
  u16*   qlo   = (u16*)(ws + WS_QLO);
  u16*   khi   = (u16*)(ws + WS_KHI);
  u16*   klo   = (u16*)(ws + WS_KLO);
  u16*   kT    = (u16*)(ws + WS_KT);
  float* knorm = (float*)(ws + WS_KNORM);
  u32*   count = (u32*)(ws + WS_CNT);
  u32*   offs  = (u32*)(ws + WS_OFFS);
  u32*   cursor= (u32*)(ws + WS_CUR);
  float* rn    = (float*)(ws + WS_RN);
  float* cmax  = (float*)(ws + WS_CMAX);
  float* csum  = (float*)(ws + WS_CSUM);
  int*   argm  = (int*)(ws + WS_ARGM);
  float* wgt   = (float*)(ws + WS_WGT);
  float* emax  = (float*)(ws + WS_EMAX);
  float* scal  = (float*)(ws + WS_SCAL);
  u32*   list  = (u32*)(ws + WS_PMAX);
  float* pm2   = (float*)(ws + WS_PM2);
  float* ps2   = (float*)(ws + WS_PS2);
  u16*   sm16  = (u16*)(ws + WS_SM16);

  float* S   = out + O2;   // scratch then sq (overwritten in place by k_row)
  float* sm  = out + O3;
  float* um  = out + O1;

  k_pre    <<<672,  256, 0, stream>>>(keys, ent, query, out, khi, klo, knorm, kT, emax, qhi, qlo, rn);
  k_score  <<<1024, 256, 0, stream>>>(qhi, qlo, khi, klo, S, pm2, ps2);
  k_colfin <<<16,   256, 0, stream>>>(pm2, ps2, cmax, csum, emax, scal, count);
  k_row    <<<4096, 256, 0, stream>>>(S, sm, sm16, cmax, csum, rn, knorm, ent, scal, argm, wgt, count, scal /*sim at [0]*/);
  k_scan   <<<1,    256, 0, stream>>>(count, offs, cursor);
  k_bucket <<<64,   256, 0, stream>>>(argm, cursor, list);
  k_gather <<<1024, 128, 0, stream>>>(qhi, qlo, offs, list, wgt, keys, um, scal);
  k_concat <<<512,  256, 0, stream>>>(kT, sm16, out);
  k_gram   <<<256,  256, 0, stream>>>(um, scal);
  k_final  <<<1,      1, 0, stream>>>(scal, out);
}

// Round 4
// 478.172 us; speedup vs baseline: 1.0638x; 1.0638x over previous
//
#include <hip/hip_runtime.h>

typedef unsigned int  u32;
typedef unsigned short u16;
typedef __bf16 bf16x8 __attribute__((ext_vector_type(8)));
typedef float  f32x4  __attribute__((ext_vector_type(4)));

// ---- output float offsets (return-order concat) ----
#define O1 16777216    // updated_memory [1024,512]
#define O2 17301504    // sq [16384,1024]  (used as S scratch first, overwritten in place)
#define O3 34078720    // sm [16384,1024]
#define O4 50855936    // diversity_loss_updated
#define O5 50855937    // similarity_loss

// ---- ws byte offsets ----
#define WS_QHI   0u
#define WS_QLO   16777216u
#define WS_KHI   33554432u
#define WS_KLO   34603008u
#define WS_KT    35651584u
#define WS_KNORM 36700160u
#define WS_CNT   36704256u   // u32[1024]
#define WS_OFFS  36708352u   // u32[1025]
#define WS_CUR   36712704u   // u32[1024]
#define WS_RN    36769792u
#define WS_PMAX  36835328u   // reused as list[16384]
#define WS_CMAX  36966400u
#define WS_CSUM  36970496u
#define WS_ARGM  36974592u
#define WS_WGT   37040128u
#define WS_GCOL  37105664u   // f32[1024] exp(-cmax)/csum
#define WS_EMAX  37199872u   // f32[32] maxent partials
#define WS_SCAL  39202816u   // [0]=sim_acc [1]=maxent [2]=div_acc [3]=diag_acc
#define WS_PM2   39203840u   // pmax2 [128][1024] f32 = 512KB
#define WS_PS2   39728128u   // psum2 [128][1024] f32 = 512KB
#define WS_SM16  40252416u   // sm bf16 [16384][1024] = 32MB  (ends ~73.8MB)

__device__ __forceinline__ u16 bf_rne(float f){
  u32 u = __float_as_uint(f);
  u32 r = u + 0x7fffu + ((u >> 16) & 1u);
  return (u16)(r >> 16);
}
__device__ __forceinline__ float bf_f(u16 h){ return __uint_as_float(((u32)h) << 16); }

__device__ __forceinline__ void glds16(const void* g, void* l){
  __builtin_amdgcn_global_load_lds((const __attribute__((address_space(1))) u32*)g,
                                   (__attribute__((address_space(3))) u32*)l, 16, 0, 0);
}

// ---------------- merged preamble: keys norm/split | keysT | maxent partials | phaseA ----------------
__global__ __launch_bounds__(256) void k_pre(
    const float* __restrict__ keys, const float* __restrict__ ent,
    const float* __restrict__ query, float* __restrict__ out0,
    u16* __restrict__ khi, u16* __restrict__ klo, float* __restrict__ knorm,
    u16* __restrict__ kT, float* __restrict__ emax,
    u16* __restrict__ qhi, u16* __restrict__ qlo, float* __restrict__ rn_g){
  __shared__ float shmem[64*65 + 256 + 64];
  float* tile = shmem;
  float* red  = shmem + 64*65;
  float* sinv = red + 256;
  int bx = blockIdx.x; int t = threadIdx.x;

  if (bx < 256){
    int wave = t >> 6, l = t & 63;
    int m = bx*4 + wave;
    const float* kr = keys + (size_t)m*512 + l*8;
    float f[8];
    #pragma unroll
    for (int i=0;i<8;i++) f[i] = kr[i];
    float ss = 0.f;
    #pragma unroll
    for (int i=0;i<8;i++) ss += f[i]*f[i];
    for (int o=32;o>0;o>>=1) ss += __shfl_xor(ss,o);
    if (l == 0) knorm[m] = sqrtf(ss);
    u32 hh[4], ll[4];
    #pragma unroll
    for (int i=0;i<4;i++){
      u16 h0 = bf_rne(f[2*i]);   u16 l0 = bf_rne(f[2*i]   - bf_f(h0));
      u16 h1 = bf_rne(f[2*i+1]); u16 l1 = bf_rne(f[2*i+1] - bf_f(h1));
      hh[i] = (u32)h0 | ((u32)h1<<16);
      ll[i] = (u32)l0 | ((u32)l1<<16);
    }
    *(uint4*)&khi[(size_t)m*512 + l*8] = make_uint4(hh[0],hh[1],hh[2],hh[3]);
    *(uint4*)&klo[(size_t)m*512 + l*8] = make_uint4(ll[0],ll[1],ll[2],ll[3]);
  } else if (bx < 384){
    int g = bx - 256;
    int m0 = (g & 15)*64, c0 = (g >> 4)*64;
    int j = t & 63; int ig = t >> 6;
    #pragma unroll 4
    for (int ii=0; ii<16; ++ii){
      int i = ig*16 + ii;
      tile[i*65 + j] = keys[(size_t)(m0+i)*512 + c0 + j];
    }
    __syncthreads();
    #pragma unroll 4
    for (int ii=0; ii<16; ++ii){
      int i = ig*16 + ii;
      kT[(size_t)(c0+i)*1024 + m0 + j] = bf_rne(tile[j*65 + i]);
    }
  } else if (bx < 416){
    int g = bx - 384;
    int i = g*512 + t;
    float v = fmaxf(ent[i], ent[i + 256]);
    for (int o=32;o>0;o>>=1) v = fmaxf(v, __shfl_xor(v,o));
    if ((t & 63) == 0) red[t>>6] = v;
    __syncthreads();
    if (t == 0) emax[g] = fmaxf(fmaxf(red[0],red[1]), fmaxf(red[2],red[3]));
  } else {
    int bx2 = bx - 416;
    int b = bx2 >> 4; int hw0 = (bx2 & 15)*64;
    int hw = t & 63; int cg = t >> 6;
    const float* qb = query + (size_t)b*524288 + hw0 + hw;
    float p = 0.f;
    for (int c = cg; c < 512; c += 4){ float v = qb[(size_t)c*1024]; p += v*v; }
    red[cg*64 + hw] = p;
    __syncthreads();
    if (t < 64){
      float ss = red[t] + red[64+t] + red[128+t] + red[192+t];
      float nrm = sqrtf(ss);
      float inv = 1.0f / fmaxf(nrm, 1e-12f);
      sinv[t] = inv;
      rn_g[b*1024 + hw0 + t] = nrm * inv;
    }
    __syncthreads();
    int nl = t >> 2, cq = t & 3;
    int n = b*1024 + hw0 + nl;
    float invv = sinv[hw];
    for (int cb = 0; cb < 8; ++cb){
      int cbase = cb*64;
      #pragma unroll 4
      for (int i = 0; i < 16; ++i){
        int cl = cg*16 + i;
        int c = cbase + cl;
        float v = query[(size_t)b*524288 + (size_t)c*1024 + hw0 + hw] * invv;
        tile[cl*65 + hw] = v;
        out0[(size_t)b*1048576 + (size_t)c*1024 + hw0 + hw] = v;
      }
      __syncthreads();
      u32 hh[8], ll[8];
      #pragma unroll
      for (int p2 = 0; p2 < 8; ++p2){
        float f0 = tile[(cq*16 + p2*2)*65 + nl];
        float f1 = tile[(cq*16 + p2*2 + 1)*65 + nl];
        u16 h0 = bf_rne(f0); u16 lo0 = bf_rne(f0 - bf_f(h0));
        u16 h1 = bf_rne(f1); u16 lo1 = bf_rne(f1 - bf_f(h1));
        hh[p2] = (u32)h0 | ((u32)h1 << 16);
        ll[p2] = (u32)lo0 | ((u32)lo1 << 16);
      }
      size_t base = (size_t)n*512 + cbase + cq*16;
      *(uint4*)&qhi[base]     = make_uint4(hh[0],hh[1],hh[2],hh[3]);
      *(uint4*)&qhi[base + 8] = make_uint4(hh[4],hh[5],hh[6],hh[7]);
      *(uint4*)&qlo[base]     = make_uint4(ll[0],ll[1],ll[2],ll[3]);
      *(uint4*)&qlo[base + 8] = make_uint4(ll[4],ll[5],ll[6],ll[7]);
      __syncthreads();
    }
  }
}

// ---------------- score GEMM: S = qr @ keys^T, split-bf16 (3 MFMA terms) ----------------
// R2 structure (m97-style single-buffer, BK=64, 2 barriers/kit), XCD-swizzled.
// MFMA triple reordered into 3 independent passes (same per-acc order: bit-identical).
__global__ __launch_bounds__(256) void k_score(const u16* __restrict__ qhi, const u16* __restrict__ qlo,
    const u16* __restrict__ khi, const u16* __restrict__ klo, float* __restrict__ S,
    float* __restrict__ pm2, float* __restrict__ ps2){
  __shared__ u16 sAh[8192], sAl[8192], sBh[8192], sBl[8192];  // 4 x 16KB = 64KB
  int tid = threadIdx.x;
  int wg = ((blockIdx.x & 7) << 7) + (blockIdx.x >> 3);   // bijective XCD swizzle (1024 wgs)
  int nt = wg >> 3, mt = wg & 7;
  int nBase = nt*128, mBase = mt*128;
  int wave = tid >> 6, lane = tid & 63;
  int rw = (wave>>1)*64, cw = (wave&1)*64;
  int m16 = lane & 15, q4 = lane >> 4;
  f32x4 acc[4][4] = {};
  int srow = tid >> 3, sg = tid & 7;
  for (int kit = 0; kit < 8; ++kit){
    int k0 = kit*64;
    #pragma unroll
    for (int it = 0; it < 4; ++it){
      int row = it*32 + srow;
      int gsw = (sg ^ (row & 7)) * 8;
      int lo = it*2048 + tid*8;
      glds16(qhi + (size_t)(nBase + row)*512 + k0 + gsw, &sAh[lo]);
      glds16(qlo + (size_t)(nBase + row)*512 + k0 + gsw, &sAl[lo]);
      glds16(khi + (size_t)(mBase + row)*512 + k0 + gsw, &sBh[lo]);
      glds16(klo + (size_t)(mBase + row)*512 + k0 + gsw, &sBl[lo]);
    }
    __syncthreads();
    #pragma unroll
    for (int ks = 0; ks < 2; ++ks){
      bf16x8 a0[4], a1[4], b0[4], b1[4];
      int g = ks*4 + q4;
      #pragma unroll
      for (int i=0;i<4;i++){
        int r = rw + i*16 + m16;
        int off = r*64 + (g ^ (r&7))*8;
        a0[i] = *(const bf16x8*)&sAh[off];
        a1[i] = *(const bf16x8*)&sAl[off];
      }
      #pragma unroll
      for (int j=0;j<4;j++){
        int r = cw + j*16 + m16;
        int off = r*64 + (g ^ (r&7))*8;
        b0[j] = *(const bf16x8*)&sBh[off];
        b1[j] = *(const bf16x8*)&sBl[off];
      }
      // 3 passes of 16 independent MFMAs (per-acc order unchanged: a0b0, a0b1, a1b0)
      #pragma unroll
      for (int i=0;i<4;i++)
        #pragma unroll
        for (int j=0;j<4;j++)
          acc[i][j] = __builtin_amdgcn_mfma_f32_16x16x32_bf16(a0[i], b0[j], acc[i][j], 0,0,0);
      #pragma unroll
      for (int i=0;i<4;i++)
        #pragma unroll
        for (int j=0;j<4;j++)
          acc[i][j] = __builtin_amdgcn_mfma_f32_16x16x32_bf16(a0[i], b1[j], acc[i][j], 0,0,0);
      #pragma unroll
      for (int i=0;i<4;i++)
        #pragma unroll
        for (int j=0;j<4;j++)
          acc[i][j] = __builtin_amdgcn_mfma_f32_16x16x32_bf16(a1[i], b0[j], acc[i][j], 0,0,0);
    }
    __syncthreads();
  }
  // ---- S store ----
  #pragma unroll
  for (int i=0;i<4;i++){
    int rbase = nBase + rw + i*16 + q4*4;
    #pragma unroll
    for (int j=0;j<4;j++){
      int col = mBase + cw + j*16 + m16;
      #pragma unroll
      for (int r=0;r<4;r++)
        S[(size_t)(rbase + r)*1024 + col] = acc[i][j][r];
    }
  }
  // ---- fused column-softmax partials over this block's 128 rows ----
  float* lm = (float*)sAh;        // [4 waves][4 j][16 m16]
  float* ls = lm + 256;
  #pragma unroll
  for (int j=0;j<4;j++){
    float cm = -3.4e38f;
    #pragma unroll
    for (int i=0;i<4;i++)
      #pragma unroll
      for (int r=0;r<4;r++) cm = fmaxf(cm, acc[i][j][r]);
    cm = fmaxf(cm, __shfl_xor(cm, 16));
    cm = fmaxf(cm, __shfl_xor(cm, 32));
    float cs = 0.f;
    #pragma unroll
    for (int i=0;i<4;i++)
      #pragma unroll
      for (int r=0;r<4;r++) cs += __expf(acc[i][j][r] - cm);
    cs += __shfl_xor(cs, 16);
    cs += __shfl_xor(cs, 32);
    if (lane < 16){
      lm[(wave*4 + j)*16 + m16] = cm;
      ls[(wave*4 + j)*16 + m16] = cs;
    }
  }
  __syncthreads();
  if (tid < 128){
    int w = tid >> 6;
    int x = tid & 63;
    int j = x >> 4, c16 = x & 15;
    float m0 = lm[(w*4 + j)*16 + c16],     s0 = ls[(w*4 + j)*16 + c16];
    float m1 = lm[((w+2)*4 + j)*16 + c16], s1 = ls[((w+2)*4 + j)*16 + c16];
    float M  = fmaxf(m0, m1);
    float Sv = s0*__expf(m0 - M) + s1*__expf(m1 - M);
    int col = mBase + w*64 + j*16 + c16;
    pm2[nt*1024 + col] = M;
    ps2[nt*1024 + col] = Sv;
  }
}

// ---------------- column finalize + housekeeping (count/scal zero, maxent reduce, gcol) ----------------
__global__ __launch_bounds__(256) void k_colfin(const float* __restrict__ pm2, const float* __restrict__ ps2,
    float* __restrict__ cmax, float* __restrict__ csum, float* __restrict__ gcol,
    const float* __restrict__ emax, float* __restrict__ scal, u32* __restrict__ count){
  int bx = blockIdx.x, t = threadIdx.x;
  if (bx < 4) count[bx*256 + t] = 0u;
  if (bx == 4 && t == 0){
    float mx = emax[0];
    for (int i=1;i<32;i++) mx = fmaxf(mx, emax[i]);
    scal[0] = 0.f; scal[1] = mx; scal[2] = 0.f; scal[3] = 0.f;
  }
  int col = bx*64 + (t & 63);
  int grp = t >> 6;
  float M = -3.4e38f, s = 0.f;
  for (int ch = grp*32; ch < grp*32 + 32; ++ch){
    float mi = pm2[ch*1024 + col], si = ps2[ch*1024 + col];
    float nm = fmaxf(M, mi);
    s = s*__expf(M - nm) + si*__expf(mi - nm);
    M = nm;
  }
  __shared__ float gm[256], gs[256];
  gm[t] = M; gs[t] = s;
  __syncthreads();
  if (t < 64){
    float MM = gm[t], ss2 = gs[t];
    #pragma unroll
    for (int g2=1; g2<4; ++g2){
      float mi = gm[g2*64 + t], si = gs[g2*64 + t];
      float nm = fmaxf(MM, mi);
      ss2 = ss2*__expf(MM - nm) + si*__expf(mi - nm);
      MM = nm;
    }
    cmax[col] = MM; csum[col] = ss2;
    gcol[col] = __expf(-MM) / ss2;
  }
}

// ---------------- row softmax: sm out (+bf16 copy), sq in-place over S, argmax/cos/w/count ----------------
// sq factorized: sq = e[j] * exp(m) * gcol[col]   (one exp per row instead of 1024 exps+divs)
__global__ __launch_bounds__(256) void k_row(float* __restrict__ S, float* __restrict__ sm,
    u16* __restrict__ sm16,
    const float* __restrict__ cmax, const float* __restrict__ gcol,
    const float* __restrict__ rn, const float* __restrict__ knorm,
    const float* __restrict__ ent, const float* __restrict__ scal,
    int* __restrict__ argm, float* __restrict__ wgt, u32* __restrict__ count,
    float* __restrict__ sim_acc){
  int wave = threadIdx.x >> 6, lane = threadIdx.x & 63;
  int n = blockIdx.x*4 + wave;
  float4 v[4];
  const float4* Sr = (const float4*)(S + (size_t)n*1024);
  #pragma unroll
  for (int j=0;j<4;j++) v[j] = Sr[j*64 + lane];
  float m = -3.4e38f; int gi = 0;
  #pragma unroll
  for (int j=0;j<4;j++){
    int c0 = j*256 + lane*4;
    if (v[j].x > m){ m=v[j].x; gi=c0; }
    if (v[j].y > m){ m=v[j].y; gi=c0+1; }
    if (v[j].z > m){ m=v[j].z; gi=c0+2; }
    if (v[j].w > m){ m=v[j].w; gi=c0+3; }
  }
  for (int o=32;o>0;o>>=1){
    float om = __shfl_xor(m,o); int oi = __shfl_xor(gi,o);
    if (om > m || (om == m && oi < gi)){ m = om; gi = oi; }
  }
  float4 e[4]; float s = 0.f;
  #pragma unroll
  for (int j=0;j<4;j++){
    e[j].x = __expf(v[j].x - m); e[j].y = __expf(v[j].y - m);
    e[j].z = __expf(v[j].z - m); e[j].w = __expf(v[j].w - m);
    s += e[j].x + e[j].y + e[j].z + e[j].w;
  }
  for (int o=32;o>0;o>>=1) s += __shfl_xor(s,o);
  float ri = 1.f/s;
  float em = __expf(m);
  float4* smr = (float4*)(sm + (size_t)n*1024);
  #pragma unroll
  for (int j=0;j<4;j++){
    float4 t2; t2.x=e[j].x*ri; t2.y=e[j].y*ri; t2.z=e[j].z*ri; t2.w=e[j].w*ri;
    smr[j*64 + lane] = t2;
    u32 w0 = (u32)bf_rne(t2.x) | ((u32)bf_rne(t2.y) << 16);
    u32 w1 = (u32)bf_rne(t2.z) | ((u32)bf_rne(t2.w) << 16);
    *(uint2*)&sm16[(size_t)n*1024 + j*256 + lane*4] = make_uint2(w0, w1);
  }
  float4* sqr = (float4*)(S + (size_t)n*1024);
  #pragma unroll
  for (int j=0;j<4;j++){
    int c0 = j*256 + lane*4;
    float4 g4 = *(const float4*)(gcol + c0);
    float4 q;
    q.x = e[j].x * (em * g4.x);
    q.y = e[j].y * (em * g4.y);
    q.z = e[j].z * (em * g4.z);
    q.w = e[j].w * (em * g4.w);
    sqr[j*64 + lane] = q;
  }
  __shared__ float simw[4];
  if (lane == 0){
    float en = ent[n];
    float cosv = m / fmaxf(rn[n]*knorm[gi], 1e-8f);
    simw[wave] = (1.f - cosv)*en;
    float w = __expf(m - cmax[gi]) * en / scal[1];
    wgt[n] = w; argm[n] = gi;
    atomicAdd(&count[gi], 1u);
  }
  __syncthreads();
  if (threadIdx.x == 0)
    atomicAdd(sim_acc, simw[0]+simw[1]+simw[2]+simw[3]);
}

// ---------------- exclusive scan of 1024 counts -> offs + cursor ----------------
__global__ __launch_bounds__(256) void k_scan(const u32* __restrict__ count,
    u32* __restrict__ offs, u32* __restrict__ cursor){
  int t = threadIdx.x;
  u32 v0 = count[t*4], v1 = count[t*4+1], v2 = count[t*4+2], v3 = count[t*4+3];
  u32 s = v0+v1+v2+v3;
  u32 x = s;
  for (int o=1;o<64;o<<=1){ u32 y = __shfl_up(x,o); if ((t&63) >= o) x += y; }
  __shared__ u32 wsum[4];
  if ((t&63) == 63) wsum[t>>6] = x;
  __syncthreads();
  u32 wb = 0;
  for (int wv=0; wv < (t>>6); ++wv) wb += wsum[wv];
  u32 excl = wb + x - s;
  u32 o0 = excl, o1 = excl+v0, o2 = excl+v0+v1, o3 = excl+v0+v1+v2;
  offs[t*4]=o0; offs[t*4+1]=o1; offs[t*4+2]=o2; offs[t*4+3]=o3;
  cursor[t*4]=o0; cursor[t*4+1]=o1; cursor[t*4+2]=o2; cursor[t*4+3]=o3;
  if (t == 255) offs[1024] = 16384u;
}

// ---------------- bucket fill ----------------
__global__ __launch_bounds__(256) void k_bucket(const int* __restrict__ argm,
    u32* __restrict__ cursor, u32* __restrict__ list){
  int n = blockIdx.x*256 + threadIdx.x;
  int g = argm[n];
  u32 pos = atomicAdd(&cursor[g], 1u);
  list[pos] = n;
}

// ---------------- gather segment-sum + fused fnorm: out1 = l2norm(sum + keys) ----------------
__global__ __launch_bounds__(128) void k_gather(const u16* __restrict__ qhi, const u16* __restrict__ qlo,
    const u32* __restrict__ offs, const u32* __restrict__ list, const float* __restrict__ wgt,
    const float* __restrict__ keys, float* __restrict__ out1, float* __restrict__ scal){
  int m = blockIdx.x, t = threadIdx.x;
  int c0 = t*4;
  float a0=0.f,a1=0.f,a2=0.f,a3=0.f;
  u32 beg = offs[m], end = offs[m+1];
  for (u32 r = beg; r < end; ++r){
    int n = (int)list[r];
    float w = wgt[n];
    uint2 hh = *(const uint2*)&qhi[(size_t)n*512 + c0];
    uint2 ll = *(const uint2*)&qlo[(size_t)n*512 + c0];
    float f0 = bf_f((u16)(hh.x & 0xffffu)) + bf_f((u16)(ll.x & 0xffffu));
    float f1 = bf_f((u16)(hh.x >> 16))     + bf_f((u16)(ll.x >> 16));
    float f2 = bf_f((u16)(hh.y & 0xffffu)) + bf_f((u16)(ll.y & 0xffffu));
    float f3 = bf_f((u16)(hh.y >> 16))     + bf_f((u16)(ll.y >> 16));
    a0 += w*f0; a1 += w*f1; a2 += w*f2; a3 += w*f3;
  }
  float4 k4 = *(const float4*)(keys + (size_t)m*512 + c0);
  float u0 = a0 + k4.x, u1 = a1 + k4.y, u2 = a2 + k4.z, u3 = a3 + k4.w;
  float ss = u0*u0 + u1*u1 + u2*u2 + u3*u3;
  for (int o=32;o>0;o>>=1) ss += __shfl_xor(ss,o);
  __shared__ float r2[2];
  if ((t&63) == 0) r2[t>>6] = ss;
  __syncthreads();
  float tot = r2[0] + r2[1];
  float inv = 1.f / fmaxf(sqrtf(tot), 1e-12f);
  float4 o4; o4.x=u0*inv; o4.y=u1*inv; o4.z=u2*inv; o4.w=u3*inv;
  *(float4*)(out1 + (size_t)m*512 + c0) = o4;
  if (t == 0){
    float s2 = tot*inv*inv;
    atomicAdd(scal + 3, s2*s2);
  }
}

// ---------------- concat GEMM: out0 upper half = (sm @ keys) transposed to BCHW ----------------
// R2 structure (single-buffer BK=64), XCD-swizzled.
__global__ __launch_bounds__(256) void k_concat(const u16* __restrict__ kT, const u16* __restrict__ sm16,
    float* __restrict__ out0){
  __shared__ u16 sA[8192];       // keysT tile 128x64 (swizzled)
  __shared__ u16 sB[8192];       // sm16 tile 128x64 (swizzled)
  int tid = threadIdx.x;
  int wg = ((blockIdx.x & 7) << 6) + (blockIdx.x >> 3);   // bijective XCD swizzle (512 wgs)
  int ct = wg & 3, nt = wg >> 2;
  int cBase = ct*128, nBase = nt*128;
  int wave = tid>>6, lane = tid&63;
  int rw = (wave>>1)*64, cw = (wave&1)*64;
  int m16 = lane&15, q4 = lane>>4;
  f32x4 acc[4][4] = {};
  int srow = tid>>3, sg = tid&7;
  for (int kit=0; kit<16; ++kit){
    int k0 = kit*64;
    #pragma unroll
    for (int it=0; it<4; ++it){
      int row = it*32 + srow;
      int gsw = (sg ^ (row & 7)) * 8;
      int lo = it*2048 + tid*8;
      glds16(kT   + (size_t)(cBase + row)*1024 + k0 + gsw, &sA[lo]);
      glds16(sm16 + (size_t)(nBase + row)*1024 + k0 + gsw, &sB[lo]);
    }
    __syncthreads();
    #pragma unroll
    for (int ks=0; ks<2; ++ks){
      bf16x8 a[4], b[4];
      int g = ks*4 + q4;
      #pragma unroll
      for (int i=0;i<4;i++){
        int r = rw + i*16 + m16;
        a[i] = *(const bf16x8*)&sA[r*64 + (g ^ (r&7))*8];
      }
      #pragma unroll
      for (int j=0;j<4;j++){
        int r = cw + j*16 + m16;
        b[j] = *(const bf16x8*)&sB[r*64 + (g ^ (r&7))*8];
      }
      #pragma unroll
      for (int i=0;i<4;i++)
        #pragma unroll
        for (int j=0;j<4;j++)
          acc[i][j] = __builtin_amdgcn_mfma_f32_16x16x32_bf16(a[i], b[j], acc[i][j], 0,0,0);
    }
    __syncthreads();
  }
  #pragma unroll
  for (int i=0;i<4;i++){
    int c = cBase + rw + i*16 + q4*4;
    #pragma unroll
    for (int j=0;j<4;j++){
      int n = nBase + cw + j*16 + m16;
      int b2 = n >> 10, hw = n & 1023;
      #pragma unroll
      for (int r=0;r<4;r++)
        out0[(size_t)b2*1048576 + (size_t)(512 + c + r)*1024 + hw] = acc[i][j][r];
    }
  }
}

// ---------------- gram diversity: sum over (c1,c2) of (U^T U)^2 ----------------
__global__ __launch_bounds__(256) void k_gram(const float* __restrict__ U, float* __restrict__ scal){
  __shared__ float Ua[64*34], Ub[64*34];
  int bx = blockIdx.x & 15, by = blockIdx.x >> 4;
  int t = threadIdx.x;
  int c1 = (t >> 4)*2, c2 = (t & 15)*2;
  float d00=0,d01=0,d10=0,d11=0;
  for (int ch=0; ch<16; ++ch){
    #pragma unroll
    for (int j=0;j<8;j++){
      int flat = j*256 + t;
      int ml = flat >> 5, c = flat & 31;
      Ua[ml*34 + c] = U[(size_t)(ch*64 + ml)*512 + bx*32 + c];
      Ub[ml*34 + c] = U[(size_t)(ch*64 + ml)*512 + by*32 + c];
    }
    __syncthreads();
    #pragma unroll 8
    for (int ml=0; ml<64; ++ml){
      float2 a = *(const float2*)&Ua[ml*34 + c1];
      float2 b = *(const float2*)&Ub[ml*34 + c2];
      d00 += a.x*b.x; d01 += a.x*b.y; d10 += a.y*b.x; d11 += a.y*b.y;
    }
    __syncthreads();
  }
  float loc = d00*d00 + d01*d01 + d10*d10 + d11*d11;
  for (int o=32;o>0;o>>=1) loc += __shfl_xor(loc,o);
  __shared__ float r4[4];
  if ((t&63) == 0) r4[t>>6] = loc;
  __syncthreads();
  if (t == 0) atomicAdd(scal + 2, r4[0]+r4[1]+r4[2]+r4[3]);
}

// ---------------- final scalars ----------------
__global__ void k_final(const float* __restrict__ scal, float* __restrict__ out){
  out[O4] = (scal[2] - scal[3]) * (1.0f/1047552.0f);
  out[O5] = scal[0];
}

extern "C" void kernel_launch(void* const* d_in, const int* in_sizes, int n_in,
                              void* d_out, int out_size, void* d_ws, size_t ws_size,
                              hipStream_t stream) {
  const float* query = (const float*)d_in[0];
  const float* keys  = (const float*)d_in[1];
  const float* ent   = (const float*)d_in[2];
  float* out  = (float*)d_out;
  char*  ws   = (char*)d_ws;

  u16*   qhi   = (u16*)(ws + WS_QHI);
  u16*   qlo   = (u16*)(ws + WS_QLO);
  u16*   khi   = (u16*)(ws + WS_KHI);
  u16*   klo   = (u16*)(ws + WS_KLO);
  u16*   kT    = (u16*)(ws + WS_KT);
  float* knorm = (float*)(ws + WS_KNORM);
  u32*   count = (u32*)(ws + WS_CNT);
  u32*   offs  = (u32*)(ws + WS_OFFS);
  u32*   cursor= (u32*)(ws + WS_CUR);
  float* rn    = (float*)(ws + WS_RN);
  float* cmax  = (float*)(ws + WS_CMAX);
  float* csum  = (float*)(ws + WS_CSUM);
  float* gcol  = (float*)(ws + WS_GCOL);
  int*   argm  = (int*)(ws + WS_ARGM);
  float* wgt   = (float*)(ws + WS_WGT);
  float* emax  = (float*)(ws + WS_EMAX);
  float* scal  = (float*)(ws + WS_SCAL);
  u32*   list  = (u32*)(ws + WS_PMAX);
  float* pm2   = (float*)(ws + WS_PM2);
  float* ps2   = (float*)(ws + WS_PS2);
  u16*   sm16  = (u16*)(ws + WS_SM16);

  float* S   = out + O2;   // scratch then sq (overwritten in place by k_row)
  float* sm  = out + O3;
  float* um  = out + O1;

  k_pre    <<<672,  256, 0, stream>>>(keys, ent, query, out, khi, klo, knorm, kT, emax, qhi, qlo, rn);
  k_score  <<<1024, 256, 0, stream>>>(qhi, qlo, khi, klo, S, pm2, ps2);
  k_colfin <<<16,   256, 0, stream>>>(pm2, ps2, cmax, csum, gcol, emax, scal, count);
  k_row    <<<4096, 256, 0, stream>>>(S, sm, sm16, cmax, gcol, rn, knorm, ent, scal, argm, wgt, count, scal /*sim at [0]*/);
  k_scan   <<<1,    256, 0, stream>>>(count, offs, cursor);
  k_bucket <<<64,   256, 0, stream>>>(argm, cursor, list);
  k_gather <<<1024, 128, 0, stream>>>(qhi, qlo, offs, list, wgt, keys, um, scal);
  k_concat <<<512,  256, 0, stream>>>(kT, sm16, out);
  k_gram   <<<256,  256, 0, stream>>>(um, scal);
  k_final  <<<1,      1, 0, stream>>>(scal, out);
}